// Round 1
// baseline (1513.306 us; speedup 1.0000x reference)
//
#include <hip/hip_runtime.h>
#include <hip/hip_bf16.h>

#define B_  64
#define TX  128
#define H_  1024
#define E_  512
#define KY  32000
#define H2  2048   // 2H
#define H3  3072   // 3H
#define EC  2560   // E+2H
#define M_  (TX*B_) // 8192

// ---------------- K1: hpart[b][h] = ab1[h] + hidden[b,:] . aW1[h, :H] ----------------
__global__ void k1_hpart(const float* __restrict__ hidden, const float* __restrict__ aW1,
                         const float* __restrict__ ab1, float* __restrict__ hpart) {
  int b = blockIdx.y;
  int wave = threadIdx.x >> 6;
  int lane = threadIdx.x & 63;
  int h = blockIdx.x * 4 + wave;
  const float* wrow = aW1 + (size_t)h * H3;
  const float* hrow = hidden + b * H_;
  float acc = 0.f;
  for (int j = 0; j < H_ / 64; ++j) {
    int i = j * 64 + lane;
    acc += hrow[i] * wrow[i];
  }
  for (int off = 32; off; off >>= 1) acc += __shfl_down(acc, off);
  if (lane == 0) hpart[b * H_ + h] = acc + ab1[h];
}

// ---------------- K2: big GEMM (8192x2048 @ 2048x1024) + tanh + aW2-reduce ----------------
// scorepart[nblk][m] = sum over this block's 64 n of aW2[n]*tanh(hpart[b][n] + C[m][n])
__global__ __launch_bounds__(256) void k2_gemm_score(
    const float* __restrict__ enc, const float* __restrict__ aW1,
    const float* __restrict__ hpart, const float* __restrict__ aW2,
    float* __restrict__ scorepart) {
  __shared__ float As[32][68];
  __shared__ float Bs[32][68];
  __shared__ float red[64][17];
  int m0 = blockIdx.x * 64;
  int n0 = blockIdx.y * 64;
  int tid = threadIdx.x;
  int ty = tid >> 4, tx = tid & 15;
  float acc[4][4] = {};
  for (int k0 = 0; k0 < H2; k0 += 32) {
    #pragma unroll
    for (int l = 0; l < 2; ++l) {
      int fi = tid + l * 256;
      int m = fi >> 3;
      int kq = (fi & 7) * 4;
      const float4 v = *(const float4*)&enc[(size_t)(m0 + m) * H2 + k0 + kq];
      As[kq + 0][m] = v.x; As[kq + 1][m] = v.y; As[kq + 2][m] = v.z; As[kq + 3][m] = v.w;
      const float4 u = *(const float4*)&aW1[(size_t)(n0 + m) * H3 + H_ + k0 + kq];
      Bs[kq + 0][m] = u.x; Bs[kq + 1][m] = u.y; Bs[kq + 2][m] = u.z; Bs[kq + 3][m] = u.w;
    }
    __syncthreads();
    #pragma unroll
    for (int kk = 0; kk < 32; ++kk) {
      float4 av = *(const float4*)&As[kk][ty * 4];
      float4 bv = *(const float4*)&Bs[kk][tx * 4];
      float a[4] = {av.x, av.y, av.z, av.w};
      float b[4] = {bv.x, bv.y, bv.z, bv.w};
      #pragma unroll
      for (int i = 0; i < 4; ++i)
        #pragma unroll
        for (int j = 0; j < 4; ++j)
          acc[i][j] += a[i] * b[j];
    }
    __syncthreads();
  }
  #pragma unroll
  for (int i = 0; i < 4; ++i) {
    int m = m0 + ty * 4 + i;
    int bb = m & 63;
    float p = 0.f;
    #pragma unroll
    for (int j = 0; j < 4; ++j) {
      int n = n0 + tx * 4 + j;
      p += aW2[n] * tanhf(hpart[bb * H_ + n] + acc[i][j]);
    }
    red[ty * 4 + i][tx] = p;
  }
  __syncthreads();
  if (tid < 64) {
    float s = 0.f;
    #pragma unroll
    for (int j = 0; j < 16; ++j) s += red[tid][j];
    scorepart[(size_t)blockIdx.y * M_ + m0 + tid] = s;
  }
}

// ---------------- K3: softmax over t (per b), score = sum of 16 partials + ab2 ----------------
__global__ void k3_softmax(const float* __restrict__ scorepart, const float* __restrict__ ab2,
                           float* __restrict__ w) {
  int b = blockIdx.x;
  int t = threadIdx.x; // 128
  float s = ab2[0];
  for (int nb = 0; nb < 16; ++nb) s += scorepart[nb * M_ + t * B_ + b];
  __shared__ float sm[128];
  sm[t] = s; __syncthreads();
  for (int off = 64; off; off >>= 1) {
    if (t < off) sm[t] = fmaxf(sm[t], sm[t + off]);
    __syncthreads();
  }
  float mx = sm[0]; __syncthreads();
  float e = expf(s - mx);
  sm[t] = e; __syncthreads();
  for (int off = 64; off; off >>= 1) {
    if (t < off) sm[t] += sm[t + off];
    __syncthreads();
  }
  w[t * B_ + b] = e / sm[0];
}

// ---------------- K4: context[b][k] = sum_t w[t][b]*enc[t][b][k] ----------------
__global__ void k4_context(const float* __restrict__ enc, const float* __restrict__ w,
                           float* __restrict__ context) {
  int b = blockIdx.y;
  int k = blockIdx.x * 256 + threadIdx.x;
  __shared__ float wl[TX];
  if (threadIdx.x < TX) wl[threadIdx.x] = w[threadIdx.x * B_ + b];
  __syncthreads();
  float acc = 0.f;
  for (int t = 0; t < TX; ++t)
    acc += wl[t] * enc[((size_t)t * B_ + b) * H2 + k];
  context[b * H2 + k] = acc;
}

// ---------------- K5a: rnn_in = [embed, context] ----------------
__global__ void k5a_rnnin(const int* __restrict__ input, const float* __restrict__ emb_W,
                          const float* __restrict__ context, float* __restrict__ rnn_in) {
  int b = blockIdx.x;
  int tok = input[b];
  for (int c = threadIdx.x; c < EC; c += blockDim.x)
    rnn_in[b * EC + c] = (c < E_) ? emb_W[(size_t)tok * E_ + c] : context[b * H2 + (c - E_)];
}

// ---------------- generic small-M GEMM: out[b][n] = bias[n] + x[b,:] . W[n,:] ----------------
// block: 256 threads = 4 waves; wave g handles NPT n-rows, lanes = b.
template<int NPT>
__global__ __launch_bounds__(256) void k_gemm_smallM(
    const float* __restrict__ x, const float* __restrict__ W,
    const float* __restrict__ bias, float* __restrict__ out, int N, int K) {
  __shared__ float xs[128][66];   // transposed [k][b], pad 66 -> 2-way max (free)
  int tid = threadIdx.x;
  int b = tid & 63, g = tid >> 6;
  int nbase = blockIdx.x * (4 * NPT) + g * NPT;
  int lrow = tid >> 2, lquad = tid & 3;
  float acc[NPT] = {};
  for (int k0 = 0; k0 < K; k0 += 128) {
    __syncthreads();
    #pragma unroll
    for (int j = 0; j < 8; ++j) {
      int c4 = j * 4 + lquad;
      float4 v = *(const float4*)&x[(size_t)lrow * K + k0 + c4 * 4];
      xs[c4 * 4 + 0][lrow] = v.x; xs[c4 * 4 + 1][lrow] = v.y;
      xs[c4 * 4 + 2][lrow] = v.z; xs[c4 * 4 + 3][lrow] = v.w;
    }
    __syncthreads();
    for (int kb = 0; kb < 128; kb += 4) {
      float x0 = xs[kb + 0][b], x1 = xs[kb + 1][b], x2 = xs[kb + 2][b], x3 = xs[kb + 3][b];
      #pragma unroll
      for (int i = 0; i < NPT; ++i) {
        const float4 wv = *(const float4*)&W[(size_t)(nbase + i) * K + k0 + kb];
        acc[i] += x0 * wv.x + x1 * wv.y + x2 * wv.z + x3 * wv.w;
      }
    }
  }
  #pragma unroll
  for (int i = 0; i < NPT; ++i) {
    int n = nbase + i;
    out[(size_t)b * N + n] = acc[i] + bias[n];
  }
}

// ---------------- K5c: GRU gates + xcat = [h_new, context] ----------------
__global__ void k5c_gates(const float* __restrict__ gi, const float* __restrict__ gh,
                          const float* __restrict__ hidden, const float* __restrict__ context,
                          float* __restrict__ hnew_out, float* __restrict__ xcat) {
  int b = blockIdx.x;
  for (int h = threadIdx.x; h < H_; h += blockDim.x) {
    float ir = gi[b * H3 + h], iz = gi[b * H3 + H_ + h], inn = gi[b * H3 + H2 + h];
    float hr = gh[b * H3 + h], hz = gh[b * H3 + H_ + h], hn = gh[b * H3 + H2 + h];
    float r = 1.f / (1.f + expf(-(ir + hr)));
    float z = 1.f / (1.f + expf(-(iz + hz)));
    float n = tanhf(inn + r * hn);
    float hv = hidden[b * H_ + h];
    float hnew = (1.f - z) * n + z * hv;
    hnew_out[b * H_ + h] = hnew;
    xcat[b * H3 + h] = hnew;
  }
  for (int c = threadIdx.x; c < H2; c += blockDim.x)
    xcat[b * H3 + H_ + c] = context[b * H2 + c];
}

// ---------------- K7: per-row logsumexp of logits (stored in d_out) ----------------
__global__ void k7_lse(const float* __restrict__ logits, float* __restrict__ lse) {
  int b = blockIdx.x;
  const float* row = logits + (size_t)b * KY;
  __shared__ float sm[256];
  float mx = -1e30f;
  for (int k = threadIdx.x; k < KY; k += 256) mx = fmaxf(mx, row[k]);
  sm[threadIdx.x] = mx; __syncthreads();
  for (int off = 128; off; off >>= 1) {
    if (threadIdx.x < off) sm[threadIdx.x] = fmaxf(sm[threadIdx.x], sm[threadIdx.x + off]);
    __syncthreads();
  }
  mx = sm[0]; __syncthreads();
  float s = 0.f;
  for (int k = threadIdx.x; k < KY; k += 256) s += expf(row[k] - mx);
  sm[threadIdx.x] = s; __syncthreads();
  for (int off = 128; off; off >>= 1) {
    if (threadIdx.x < off) sm[threadIdx.x] += sm[threadIdx.x + off];
    __syncthreads();
  }
  if (threadIdx.x == 0) lse[b] = mx + logf(sm[0]);
}

// ---------------- K8: in-place out = logits - lse ----------------
__global__ void k8_out(float* __restrict__ outp, const float* __restrict__ lse) {
  int b = blockIdx.y;
  int k = blockIdx.x * 256 + threadIdx.x;
  size_t idx = (size_t)b * KY + k;
  outp[idx] = outp[idx] - lse[b];
}

extern "C" void kernel_launch(void* const* d_in, const int* in_sizes, int n_in,
                              void* d_out, int out_size, void* d_ws, size_t ws_size,
                              hipStream_t stream) {
  const int*   input  = (const int*)  d_in[0];
  const float* hidden = (const float*)d_in[1];
  const float* enc    = (const float*)d_in[2];
  const float* emb_W  = (const float*)d_in[3];
  const float* Wih    = (const float*)d_in[4];
  const float* Whh    = (const float*)d_in[5];
  const float* bih    = (const float*)d_in[6];
  const float* bhh    = (const float*)d_in[7];
  const float* lsm_W  = (const float*)d_in[8];
  const float* lsm_b  = (const float*)d_in[9];
  const float* aW1    = (const float*)d_in[10];
  const float* ab1    = (const float*)d_in[11];
  const float* aW2    = (const float*)d_in[12];
  const float* ab2    = (const float*)d_in[13];

  float* out   = (float*)d_out;           // [0 .. 2048000): log_softmax output (logits in place first)
  float* hnew  = out + (size_t)B_ * KY;   // [2048000 .. +65536): h_new

  float* ws = (float*)d_ws;
  float* hpart     = ws;                    // 64*1024      = 65536
  float* scorepart = hpart + 65536;         // 16*8192      = 131072
  float* w         = scorepart + 131072;    // 8192
  float* context   = w + 8192;              // 64*2048      = 131072
  float* rnn_in    = context + 131072;      // 64*2560      = 163840
  float* gi        = rnn_in + 163840;       // 64*3072      = 196608
  float* gh        = gi + 196608;           // 64*3072      = 196608
  float* xcat      = gh + 196608;           // 64*3072      = 196608
  float* lse       = xcat + 196608;         // 64
  // total ~4.46 MB of ws

  k1_hpart<<<dim3(256, 64), 256, 0, stream>>>(hidden, aW1, ab1, hpart);
  k2_gemm_score<<<dim3(M_ / 64, 16), 256, 0, stream>>>(enc, aW1, hpart, aW2, scorepart);
  k3_softmax<<<B_, TX, 0, stream>>>(scorepart, ab2, w);
  k4_context<<<dim3(H2 / 256, B_), 256, 0, stream>>>(enc, w, context);
  k5a_rnnin<<<B_, 256, 0, stream>>>(input, emb_W, context, rnn_in);
  k_gemm_smallM<4><<<H3 / 16, 256, 0, stream>>>(rnn_in, Wih, bih, gi, H3, EC);
  k_gemm_smallM<4><<<H3 / 16, 256, 0, stream>>>(hidden, Whh, bhh, gh, H3, H_);
  k5c_gates<<<B_, 256, 0, stream>>>(gi, gh, hidden, context, hnew, xcat);
  k_gemm_smallM<16><<<KY / 64, 256, 0, stream>>>(xcat, lsm_W, lsm_b, out, KY, H3);
  k7_lse<<<B_, 256, 0, stream>>>(out, lse);
  k8_out<<<dim3(KY / 256, B_), 256, 0, stream>>>(out, lse);
}